// Round 10
// baseline (173.686 us; speedup 1.0000x reference)
//
#include <hip/hip_runtime.h>
#include <hip/hip_bf16.h>

#define Bn   32768
#define Tn   200
#define In   6
#define Hn   6
#define FFn  128
#define OUTn 12
#define KP   1600   // padded K = Tn * 8 (6 h-values + 2 zero slots per step)
#define SB   64     // samples per block

typedef __attribute__((ext_vector_type(2))) float          f32x2;
typedef __attribute__((ext_vector_type(4))) float          f32x4;
typedef __attribute__((ext_vector_type(8))) short          bf16x8;
typedef __attribute__((ext_vector_type(4))) unsigned short u16x4;
typedef __attribute__((ext_vector_type(8))) unsigned short u16x8;

#define LOG2E 1.442695041f

__device__ __forceinline__ f32x2 pkfma(f32x2 a, f32x2 b, f32x2 c) {
#if __has_builtin(__builtin_elementwise_fma)
    return __builtin_elementwise_fma(a, b, c);   // -> v_pk_fma_f32
#else
    return a * b + c;
#endif
}
__device__ __forceinline__ float swap1(float v) {
    // exchange with lane^1 (pairs are even-aligned, never cross wave)
    return __int_as_float(__builtin_amdgcn_mov_dpp(__float_as_int(v), 0xB1, 0xF, 0xF, true));
}
__device__ __forceinline__ unsigned short f2bf(float v) {
    unsigned u = __float_as_uint(v);
    unsigned r = u + 0x7FFFu + ((u >> 16) & 1u);
    return (unsigned short)(r >> 16);
}

// lgkmcnt-only barrier: LDS writes visible, vmcnt loads stay in flight across it
#define BAR() do {                                          \
    asm volatile("s_waitcnt lgkmcnt(0)" ::: "memory");      \
    __builtin_amdgcn_sched_barrier(0);                      \
    __builtin_amdgcn_s_barrier();                           \
    __builtin_amdgcn_sched_barrier(0);                      \
} while (0)

// Build W1' [FFn][KP] bf16 from W1 [FFn][Tn*Hn] fp32 with the padded-slot mapping:
// slot p: 0,1,2 -> h 0,1,2 ; 4,5,6 -> h 3,4,5 ; 3,7 -> zero
__global__ void prep_kernel(const float* __restrict__ W1, unsigned short* __restrict__ W1p) {
    int idx = blockIdx.x * 256 + threadIdx.x;
    if (idx >= FFn * KP) return;
    int ff = idx / KP, kp = idx - ff * KP;
    int t = kp >> 3, p = kp & 7;
    float v = 0.f;
    if (p != 3 && p != 7) {
        int h = (p < 3) ? p : (p - 1);
        v = W1[ff * (Tn * Hn) + t * Hn + h];
    }
    W1p[idx] = f2bf(v);
}

// Compile config: 256 threads, launch_bounds(256,1), static LDS padded to
// exactly 56 KB. Compile-side: floor(160/56)=2 WGs/CU target -> 8 waves/CU
// -> 2 waves/EU -> VGPR budget 256 (r9 proved: allocator lands ~184, no
// spill). Runtime-side: 2 x 56 KB = 112 KB fits even if usable LDS/CU is
// only 128 KB (r9's 2 x 64 KB = 131072 did NOT co-reside). No amdgpu_num_vgpr
// attribute (suspected to reserve 256/wave at launch, also blocking 2/SIMD).
// Grid = 512 blocks over 256 CUs -> 2 blocks/CU -> 2 waves/SIMD.
__global__ __launch_bounds__(256, 1)
void fused_kernel(const float* __restrict__ x,
                  const float* __restrict__ W_ih, const float* __restrict__ W_hh,
                  const float* __restrict__ b_ih, const float* __restrict__ b_hh,
                  const unsigned short* __restrict__ W1p,
                  const float* __restrict__ b1,
                  const float* __restrict__ W2, const float* __restrict__ b2,
                  float* __restrict__ out)
{
    // real LDS: htile 16 KB + hidS 17 KB + W2s 6 KB = 39936 B; pad to 57344 B
    __shared__ unsigned short htile[2][8][SB][8];
    __shared__ unsigned short hidS[SB][136];
    __shared__ float          W2s[OUTn * FFn];
    __shared__ float          lds_pad[4352];     // 17408 B -> total 57344 B

    const int tid = threadIdx.x;
    const int wv  = tid >> 6;        // wave 0..3
    const int b0  = blockIdx.x * SB;

    // keep lds_pad alive: runtime condition (can't constant-fold), and a
    // store -> differently-indexed load -> global store chain (can't DSE /
    // store-forward). Never true for real inputs (b2 is finite uniform data).
    if (__float_as_uint(b2[0]) == 0x7F123456u) {
        lds_pad[tid] = b2[1];
        out[(tid * 37) & 255] = lds_pad[(tid * 53) & 4351];
    }

    if (wv < 2) {
        // ================== LSTM waves (tid 0..127) ==================
        const int sloc = tid >> 1;   // local sample 0..63
        const int role = tid & 1;    // 0: units 0..2, 1: units 3..5

        // per-lane gate weights, row-pairs packed, activation scale folded
        // (sig rows: -log2e ; g rows: +2*log2e)
        f32x2 Wx[6][6], Wh[6][6], bias2[6];
        #pragma unroll
        for (int gt = 0; gt < 4; ++gt) {
            #pragma unroll
            for (int m = 0; m < 3; ++m) {
                const int j = gt * 3 + m;
                const int p = j >> 1, hf = j & 1;
                const int row = gt * 6 + role * 3 + m;
                const float sc = (gt == 2) ? (2.f * LOG2E) : (-LOG2E);
                #pragma unroll
                for (int k = 0; k < 6; ++k) Wx[p][k][hf] = sc * W_ih[row * 6 + k];
                #pragma unroll
                for (int k = 0; k < 3; ++k) Wh[p][k][hf]     = sc * W_hh[row * 6 + role * 3 + k];
                #pragma unroll
                for (int k = 0; k < 3; ++k) Wh[p][3 + k][hf] = sc * W_hh[row * 6 + (1 - role) * 3 + k];
                bias2[p][hf] = sc * (b_ih[row] + b_hh[row]);
            }
        }

        float hOwn[3] = {0.f, 0.f, 0.f}, hOth[3] = {0.f, 0.f, 0.f}, cS[3] = {0.f, 0.f, 0.f};

        const f32x4* xb4 = (const f32x4*)(x + (size_t)(b0 + sloc) * (Tn * In));

        auto STEPS4 = [&](const f32x4 (&bx)[6], int slot, int sbase) {
            #pragma unroll
            for (int s = 0; s < 4; ++s) {
                float xv[6];
                #pragma unroll
                for (int k = 0; k < 6; ++k) { const int fl = s * 6 + k; xv[k] = bx[fl >> 2][fl & 3]; }
                f32x2 a2[6];
                #pragma unroll
                for (int p = 0; p < 6; ++p) a2[p] = bias2[p];
                #pragma unroll
                for (int k = 0; k < 6; ++k) {
                    const f32x2 xs = (f32x2){xv[k], xv[k]};
                    #pragma unroll
                    for (int p = 0; p < 6; ++p) a2[p] = pkfma(Wx[p][k], xs, a2[p]);
                }
                #pragma unroll
                for (int k = 0; k < 3; ++k) {
                    const f32x2 hs = (f32x2){hOwn[k], hOwn[k]};
                    #pragma unroll
                    for (int p = 0; p < 6; ++p) a2[p] = pkfma(Wh[p][k], hs, a2[p]);
                }
                #pragma unroll
                for (int k = 0; k < 3; ++k) {
                    const f32x2 hs = (f32x2){hOth[k], hOth[k]};
                    #pragma unroll
                    for (int p = 0; p < 6; ++p) a2[p] = pkfma(Wh[p][3 + k], hs, a2[p]);
                }
                float av[12];
                #pragma unroll
                for (int p = 0; p < 6; ++p) { av[2 * p] = a2[p][0]; av[2 * p + 1] = a2[p][1]; }

                unsigned short hb[3];
                #pragma unroll
                for (int m = 0; m < 3; ++m) {
                    // folded: av[m]=-l2e*ai, av[3+m]=-l2e*af, av[6+m]=+2l2e*ag, av[9+m]=-l2e*ao
                    const float Ei = __builtin_amdgcn_exp2f(av[m]);
                    const float Ef = __builtin_amdgcn_exp2f(av[3 + m]);
                    const float Eg = __builtin_amdgcn_exp2f(av[6 + m]);
                    const float Eo = __builtin_amdgcn_exp2f(av[9 + m]);
                    const float fv = __builtin_amdgcn_rcpf(1.f + Ef);
                    const float ig = (Eg - 1.f) *
                                     __builtin_amdgcn_rcpf((1.f + Ei) * (1.f + Eg));
                    const float c  = fmaf(fv, cS[m], ig);
                    cS[m] = c;
                    // h = o*tanh(c) = (Ec-1)/((1+Eo)(1+Ec)); cap exp arg (NaN-safe both ends)
                    const float Ec = __builtin_amdgcn_exp2f(fminf(2.f * LOG2E * c, 60.f));
                    const float hv = (Ec - 1.f) *
                                     __builtin_amdgcn_rcpf((1.f + Eo) * (1.f + Ec));
                    hOwn[m] = hv;
                    hOth[m] = swap1(hv);
                    hb[m]   = f2bf(hv);
                }
                u16x4 hw; hw.x = hb[0]; hw.y = hb[1]; hw.z = hb[2]; hw.w = 0;
                *((u16x4*)&htile[slot][sbase + s][sloc][role * 4]) = hw;
            }
        };

        f32x4 bufA[6], bufB[6];
        #pragma unroll
        for (int q = 0; q < 6; ++q) bufA[q] = xb4[q];

        for (int g = 0; g < 25; ++g) {
            #pragma unroll
            for (int q = 0; q < 6; ++q) bufB[q] = xb4[(2 * g + 1) * 6 + q];
            STEPS4(bufA, g & 1, 0);
            if (g < 24) {
                #pragma unroll
                for (int q = 0; q < 6; ++q) bufA[q] = xb4[(2 * g + 2) * 6 + q];
            }
            STEPS4(bufB, g & 1, 4);
            BAR();
        }
        // stage W2 while helpers finish the last group
        for (int q = tid; q < OUTn * FFn; q += 128) W2s[q] = W2[q];

    } else {
        // ================== helper waves (tid 128..255) ==================
        const int wv2 = wv - 2;      // 0..1, owns FF columns wv2*64..wv2*64+63
        const int l   = tid & 63;
        const int lr  = l & 15;
        const int lg  = l >> 4;

        const unsigned short* wrow[4];
        #pragma unroll
        for (int n = 0; n < 4; ++n) wrow[n] = W1p + (size_t)(wv2 * 64 + n * 16 + lr) * KP;

        f32x4 acc[4][4];
        #pragma unroll
        for (int m = 0; m < 4; ++m)
            #pragma unroll
            for (int n = 0; n < 4; ++n)
                acc[m][n] = (f32x4){0.f, 0.f, 0.f, 0.f};

        auto LOADB = [&](int g, bf16x8 (&bf)[2][4]) {
            #pragma unroll
            for (int kc = 0; kc < 2; ++kc)
                #pragma unroll
                for (int n = 0; n < 4; ++n)
                    bf[kc][n] = *((const bf16x8*)&wrow[n][g * 64 + kc * 32 + lg * 8]);
        };

        auto MFMAG8 = [&](int slot, const bf16x8 (&bf)[2][4]) {
            #pragma unroll
            for (int kc = 0; kc < 2; ++kc) {
                bf16x8 af[4];
                #pragma unroll
                for (int m = 0; m < 4; ++m)
                    af[m] = *((const bf16x8*)&htile[slot][kc * 4 + lg][m * 16 + lr][0]);
                #pragma unroll
                for (int n = 0; n < 4; ++n)
                    #pragma unroll
                    for (int m = 0; m < 4; ++m)
                        acc[m][n] = __builtin_amdgcn_mfma_f32_16x16x32_bf16(af[m], bf[kc][n], acc[m][n], 0, 0, 0);
            }
        };

        bf16x8 bfA[2][4], bfB[2][4];
        LOADB(0, bfA);
        for (int gg = 0; gg < 12; ++gg) {
            BAR();
            LOADB(2 * gg + 1, bfB);
            MFMAG8(0, bfA);
            BAR();
            const int gn = (2 * gg + 2 < 25) ? (2 * gg + 2) : 24;
            LOADB(gn, bfA);
            MFMAG8(1, bfB);
        }
        BAR();
        MFMAG8(0, bfA);      // group 24

        // epilogue part 1: hid = relu(acc + b1) -> LDS bf16
        float b1v[4];
        #pragma unroll
        for (int n = 0; n < 4; ++n) b1v[n] = b1[wv2 * 64 + n * 16 + lr];
        #pragma unroll
        for (int m = 0; m < 4; ++m)
            #pragma unroll
            for (int n = 0; n < 4; ++n)
                #pragma unroll
                for (int r = 0; r < 4; ++r)
                    hidS[m * 16 + lg * 4 + r][wv2 * 64 + n * 16 + lr] =
                        f2bf(fmaxf(acc[m][n][r] + b1v[n], 0.f));
    }

    __syncthreads();

    // ---- epilogue part 2 (all 256 threads): out = hid @ W2^T + b2 ----
    const int s2 = tid >> 2;        // sample 0..63
    const int q  = tid & 3;         // 3 outputs each
    float oa[3];
    #pragma unroll
    for (int jj = 0; jj < 3; ++jj) oa[jj] = b2[q * 3 + jj];
    for (int k8 = 0; k8 < 16; ++k8) {
        const u16x8 hv8 = *((const u16x8*)&hidS[s2][k8 * 8]);
        #pragma unroll
        for (int e = 0; e < 8; ++e) {
            const float hv = __uint_as_float(((unsigned)(unsigned short)hv8[e]) << 16);
            const int k = k8 * 8 + e;
            #pragma unroll
            for (int jj = 0; jj < 3; ++jj)
                oa[jj] = fmaf(hv, W2s[(q * 3 + jj) * FFn + k], oa[jj]);
        }
    }
    float* op = out + (size_t)(b0 + s2) * OUTn + q * 3;
    #pragma unroll
    for (int jj = 0; jj < 3; ++jj) op[jj] = oa[jj];
}

extern "C" void kernel_launch(void* const* d_in, const int* in_sizes, int n_in,
                              void* d_out, int out_size, void* d_ws, size_t ws_size,
                              hipStream_t stream) {
    const float* x    = (const float*)d_in[0];
    const float* W_ih = (const float*)d_in[1];
    const float* W_hh = (const float*)d_in[2];
    const float* b_ih = (const float*)d_in[3];
    const float* b_hh = (const float*)d_in[4];
    const float* W1   = (const float*)d_in[5];
    const float* b1   = (const float*)d_in[6];
    const float* W2   = (const float*)d_in[7];
    const float* b2   = (const float*)d_in[8];
    unsigned short* W1p = (unsigned short*)d_ws;   // 128*1600*2B = 400 KB
    float* out = (float*)d_out;

    prep_kernel<<<(FFn * KP + 255) / 256, 256, 0, stream>>>(W1, W1p);
    fused_kernel<<<Bn / SB, 256, 0, stream>>>(x, W_ih, W_hh, b_ih, b_hh,
                                              W1p, b1, W2, b2, out);
}

// Round 11
// 122.095 us; speedup vs baseline: 1.4225x; 1.4225x over previous
//
#include <hip/hip_runtime.h>
#include <hip/hip_bf16.h>

#define Bn   32768
#define Tn   200
#define In   6
#define Hn   6
#define FFn  128
#define OUTn 12
#define KP   1600   // padded K = Tn * 8 (6 h-values + 2 zero slots per step)

typedef __attribute__((ext_vector_type(2))) float          f32x2;
typedef __attribute__((ext_vector_type(4))) float          f32x4;
typedef __attribute__((ext_vector_type(8))) short          bf16x8;
typedef __attribute__((ext_vector_type(4))) unsigned short u16x4;
typedef __attribute__((ext_vector_type(8))) unsigned short u16x8;

#define LOG2E 1.442695041f

__device__ __forceinline__ f32x2 pkfma(f32x2 a, f32x2 b, f32x2 c) {
#if __has_builtin(__builtin_elementwise_fma)
    return __builtin_elementwise_fma(a, b, c);   // -> v_pk_fma_f32
#else
    return a * b + c;
#endif
}
__device__ __forceinline__ float swap1(float v) {
    // exchange with lane^1 (pairs are even-aligned, never cross wave)
    return __int_as_float(__builtin_amdgcn_mov_dpp(__float_as_int(v), 0xB1, 0xF, 0xF, true));
}
__device__ __forceinline__ unsigned short f2bf(float v) {
    unsigned u = __float_as_uint(v);
    unsigned r = u + 0x7FFFu + ((u >> 16) & 1u);
    return (unsigned short)(r >> 16);
}

// lgkmcnt-only barrier: LDS writes visible, vmcnt loads stay in flight across it
#define BAR() do {                                          \
    asm volatile("s_waitcnt lgkmcnt(0)" ::: "memory");      \
    __builtin_amdgcn_sched_barrier(0);                      \
    __builtin_amdgcn_s_barrier();                           \
    __builtin_amdgcn_sched_barrier(0);                      \
} while (0)

// Build W1' [FFn][KP] bf16 from W1 [FFn][Tn*Hn] fp32 with the padded-slot mapping:
// slot p: 0,1,2 -> h 0,1,2 ; 4,5,6 -> h 3,4,5 ; 3,7 -> zero
__global__ void prep_kernel(const float* __restrict__ W1, unsigned short* __restrict__ W1p) {
    int idx = blockIdx.x * 256 + threadIdx.x;
    if (idx >= FFn * KP) return;
    int ff = idx / KP, kp = idx - ff * KP;
    int t = kp >> 3, p = kp & 7;
    float v = 0.f;
    if (p != 3 && p != 7) {
        int h = (p < 3) ? p : (p - 1);
        v = W1[ff * (Tn * Hn) + t * Hn + h];
    }
    W1p[idx] = f2bf(v);
}

// Occupancy plan (model validated r5-r10: VGPR budget = 512 / LDS-derived
// waves/EU; hints can only RAISE the target):
//   512-thr WG + LDS 88 KB  =>  floor(160/88) = 1 WG/CU  =>  8 waves/CU
//   =>  2 waves/EU  =>  VGPR budget 256 (expect ~184-240, no spill).
// Co-residency is INTRA-workgroup (8 waves of one WG) so the runtime
// scheduler cannot refuse it (r10 showed 2 x 56 KB WGs are not co-scheduled).
// Each SIMD gets 1 LSTM wave (wv 0-3) + 1 helper wave (wv 4-7) via wv%4.
__global__ __launch_bounds__(512, 1)
void fused_kernel(const float* __restrict__ x,
                  const float* __restrict__ W_ih, const float* __restrict__ W_hh,
                  const float* __restrict__ b_ih, const float* __restrict__ b_hh,
                  const unsigned short* __restrict__ W1p,
                  const float* __restrict__ b1,
                  const float* __restrict__ W2, const float* __restrict__ b2,
                  float* __restrict__ out)
{
    // real LDS: htile 32 KB + hidS 34 KB + W2s 6 KB = 73728 B; pad to 90112 B
    __shared__ unsigned short htile[2][8][128][8];
    __shared__ unsigned short hidS[128][136];
    __shared__ float          W2s[OUTn * FFn];
    __shared__ float          lds_pad[4096];     // 16384 B -> total 90112 B (88 KB)

    const int tid = threadIdx.x;
    const int wv  = tid >> 6;        // wave 0..7
    const int b0  = blockIdx.x * 128;

    // keep lds_pad alive (proven in r9/r10): runtime-unprovable condition on b2
    // + store -> cross-indexed load -> global store (defeats DSE/forwarding).
    // Never true for real inputs (b2 is finite uniform data).
    if (__float_as_uint(b2[0]) == 0x7F123456u) {
        lds_pad[tid] = b2[1];
        out[(tid * 37) & 255] = lds_pad[(tid * 53) & 4095];
    }

    if (wv < 4) {
        // ================== LSTM waves (tid 0..255) ==================
        const int sloc = tid >> 1;   // local sample 0..127
        const int role = tid & 1;    // 0: units 0..2, 1: units 3..5

        // per-lane gate weights, row-pairs packed, activation scale folded
        // (sig rows: -log2e ; g rows: +2*log2e)
        f32x2 Wx[6][6], Wh[6][6], bias2[6];
        #pragma unroll
        for (int gt = 0; gt < 4; ++gt) {
            #pragma unroll
            for (int m = 0; m < 3; ++m) {
                const int j = gt * 3 + m;
                const int p = j >> 1, hf = j & 1;
                const int row = gt * 6 + role * 3 + m;
                const float sc = (gt == 2) ? (2.f * LOG2E) : (-LOG2E);
                #pragma unroll
                for (int k = 0; k < 6; ++k) Wx[p][k][hf] = sc * W_ih[row * 6 + k];
                #pragma unroll
                for (int k = 0; k < 3; ++k) Wh[p][k][hf]     = sc * W_hh[row * 6 + role * 3 + k];
                #pragma unroll
                for (int k = 0; k < 3; ++k) Wh[p][3 + k][hf] = sc * W_hh[row * 6 + (1 - role) * 3 + k];
                bias2[p][hf] = sc * (b_ih[row] + b_hh[row]);
            }
        }

        float hOwn[3] = {0.f, 0.f, 0.f}, hOth[3] = {0.f, 0.f, 0.f}, cS[3] = {0.f, 0.f, 0.f};

        const f32x4* xb4 = (const f32x4*)(x + (size_t)(b0 + sloc) * (Tn * In));

        auto STEPS4 = [&](const f32x4 (&bx)[6], int slot, int sbase) {
            #pragma unroll
            for (int s = 0; s < 4; ++s) {
                float xv[6];
                #pragma unroll
                for (int k = 0; k < 6; ++k) { const int fl = s * 6 + k; xv[k] = bx[fl >> 2][fl & 3]; }
                f32x2 a2[6];
                #pragma unroll
                for (int p = 0; p < 6; ++p) a2[p] = bias2[p];
                #pragma unroll
                for (int k = 0; k < 6; ++k) {
                    const f32x2 xs = (f32x2){xv[k], xv[k]};
                    #pragma unroll
                    for (int p = 0; p < 6; ++p) a2[p] = pkfma(Wx[p][k], xs, a2[p]);
                }
                #pragma unroll
                for (int k = 0; k < 3; ++k) {
                    const f32x2 hs = (f32x2){hOwn[k], hOwn[k]};
                    #pragma unroll
                    for (int p = 0; p < 6; ++p) a2[p] = pkfma(Wh[p][k], hs, a2[p]);
                }
                #pragma unroll
                for (int k = 0; k < 3; ++k) {
                    const f32x2 hs = (f32x2){hOth[k], hOth[k]};
                    #pragma unroll
                    for (int p = 0; p < 6; ++p) a2[p] = pkfma(Wh[p][3 + k], hs, a2[p]);
                }
                float av[12];
                #pragma unroll
                for (int p = 0; p < 6; ++p) { av[2 * p] = a2[p][0]; av[2 * p + 1] = a2[p][1]; }

                unsigned short hb[3];
                #pragma unroll
                for (int m = 0; m < 3; ++m) {
                    // folded: av[m]=-l2e*ai, av[3+m]=-l2e*af, av[6+m]=+2l2e*ag, av[9+m]=-l2e*ao
                    const float Ei = __builtin_amdgcn_exp2f(av[m]);
                    const float Ef = __builtin_amdgcn_exp2f(av[3 + m]);
                    const float Eg = __builtin_amdgcn_exp2f(av[6 + m]);
                    const float Eo = __builtin_amdgcn_exp2f(av[9 + m]);
                    const float fv = __builtin_amdgcn_rcpf(1.f + Ef);
                    const float ig = (Eg - 1.f) *
                                     __builtin_amdgcn_rcpf((1.f + Ei) * (1.f + Eg));
                    const float c  = fmaf(fv, cS[m], ig);
                    cS[m] = c;
                    // h = o*tanh(c) = (Ec-1)/((1+Eo)(1+Ec)); cap exp arg (NaN-safe both ends)
                    const float Ec = __builtin_amdgcn_exp2f(fminf(2.f * LOG2E * c, 60.f));
                    const float hv = (Ec - 1.f) *
                                     __builtin_amdgcn_rcpf((1.f + Eo) * (1.f + Ec));
                    hOwn[m] = hv;
                    hOth[m] = swap1(hv);
                    hb[m]   = f2bf(hv);
                }
                u16x4 hw; hw.x = hb[0]; hw.y = hb[1]; hw.z = hb[2]; hw.w = 0;
                *((u16x4*)&htile[slot][sbase + s][sloc][role * 4]) = hw;
            }
        };

        f32x4 bufA[6], bufB[6];
        #pragma unroll
        for (int q = 0; q < 6; ++q) bufA[q] = xb4[q];

        for (int g = 0; g < 25; ++g) {
            #pragma unroll
            for (int q = 0; q < 6; ++q) bufB[q] = xb4[(2 * g + 1) * 6 + q];
            STEPS4(bufA, g & 1, 0);
            if (g < 24) {
                #pragma unroll
                for (int q = 0; q < 6; ++q) bufA[q] = xb4[(2 * g + 2) * 6 + q];
            }
            STEPS4(bufB, g & 1, 4);
            BAR();
        }
        // stage W2 while helpers finish the last group
        for (int q = tid; q < OUTn * FFn; q += 256) W2s[q] = W2[q];

    } else {
        // ================== helper waves (tid 256..511) ==================
        const int wv2 = wv - 4;      // 0..3, owns FF columns wv2*32..wv2*32+31
        const int l   = tid & 63;
        const int lr  = l & 15;
        const int lg  = l >> 4;

        const unsigned short* wrow[2];
        #pragma unroll
        for (int n = 0; n < 2; ++n) wrow[n] = W1p + (size_t)(wv2 * 32 + n * 16 + lr) * KP;

        f32x4 acc[8][2];
        #pragma unroll
        for (int m = 0; m < 8; ++m)
            #pragma unroll
            for (int n = 0; n < 2; ++n)
                acc[m][n] = (f32x4){0.f, 0.f, 0.f, 0.f};

        auto LOADB = [&](int g, bf16x8 (&bf)[2][2]) {
            #pragma unroll
            for (int kc = 0; kc < 2; ++kc)
                #pragma unroll
                for (int n = 0; n < 2; ++n)
                    bf[kc][n] = *((const bf16x8*)&wrow[n][g * 64 + kc * 32 + lg * 8]);
        };

        auto MFMAG8 = [&](int slot, const bf16x8 (&bf)[2][2]) {
            #pragma unroll
            for (int kc = 0; kc < 2; ++kc) {
                bf16x8 af[8];
                #pragma unroll
                for (int m = 0; m < 8; ++m)
                    af[m] = *((const bf16x8*)&htile[slot][kc * 4 + lg][m * 16 + lr][0]);
                #pragma unroll
                for (int n = 0; n < 2; ++n)
                    #pragma unroll
                    for (int m = 0; m < 8; ++m)
                        acc[m][n] = __builtin_amdgcn_mfma_f32_16x16x32_bf16(af[m], bf[kc][n], acc[m][n], 0, 0, 0);
            }
        };

        bf16x8 bfA[2][2], bfB[2][2];
        LOADB(0, bfA);
        for (int gg = 0; gg < 12; ++gg) {
            BAR();
            LOADB(2 * gg + 1, bfB);
            MFMAG8(0, bfA);
            BAR();
            const int gn = (2 * gg + 2 < 25) ? (2 * gg + 2) : 24;
            LOADB(gn, bfA);
            MFMAG8(1, bfB);
        }
        BAR();
        MFMAG8(0, bfA);      // group 24

        // epilogue part 1: hid = relu(acc + b1) -> LDS bf16
        float b1v[2];
        #pragma unroll
        for (int n = 0; n < 2; ++n) b1v[n] = b1[wv2 * 32 + n * 16 + lr];
        #pragma unroll
        for (int m = 0; m < 8; ++m)
            #pragma unroll
            for (int n = 0; n < 2; ++n)
                #pragma unroll
                for (int r = 0; r < 4; ++r)
                    hidS[m * 16 + lg * 4 + r][wv2 * 32 + n * 16 + lr] =
                        f2bf(fmaxf(acc[m][n][r] + b1v[n], 0.f));
    }

    __syncthreads();

    // ---- epilogue part 2 (all 512 threads): out = hid @ W2^T + b2 ----
    const int s2 = tid >> 2;        // sample 0..127
    const int q  = tid & 3;         // 3 outputs each
    float oa[3];
    #pragma unroll
    for (int jj = 0; jj < 3; ++jj) oa[jj] = b2[q * 3 + jj];
    for (int k8 = 0; k8 < 16; ++k8) {
        const u16x8 hv8 = *((const u16x8*)&hidS[s2][k8 * 8]);
        #pragma unroll
        for (int e = 0; e < 8; ++e) {
            const float hv = __uint_as_float(((unsigned)(unsigned short)hv8[e]) << 16);
            const int k = k8 * 8 + e;
            #pragma unroll
            for (int jj = 0; jj < 3; ++jj)
                oa[jj] = fmaf(hv, W2s[(q * 3 + jj) * FFn + k], oa[jj]);
        }
    }
    float* op = out + (size_t)(b0 + s2) * OUTn + q * 3;
    #pragma unroll
    for (int jj = 0; jj < 3; ++jj) op[jj] = oa[jj];
}

extern "C" void kernel_launch(void* const* d_in, const int* in_sizes, int n_in,
                              void* d_out, int out_size, void* d_ws, size_t ws_size,
                              hipStream_t stream) {
    const float* x    = (const float*)d_in[0];
    const float* W_ih = (const float*)d_in[1];
    const float* W_hh = (const float*)d_in[2];
    const float* b_ih = (const float*)d_in[3];
    const float* b_hh = (const float*)d_in[4];
    const float* W1   = (const float*)d_in[5];
    const float* b1   = (const float*)d_in[6];
    const float* W2   = (const float*)d_in[7];
    const float* b2   = (const float*)d_in[8];
    unsigned short* W1p = (unsigned short*)d_ws;   // 128*1600*2B = 400 KB
    float* out = (float*)d_out;

    prep_kernel<<<(FFn * KP + 255) / 256, 256, 0, stream>>>(W1, W1p);
    fused_kernel<<<Bn / 128, 512, 0, stream>>>(x, W_ih, W_hh, b_ih, b_hh,
                                               W1p, b1, W2, b2, out);
}